// Round 6
// baseline (136.631 us; speedup 1.0000x reference)
//
#include <hip/hip_runtime.h>

// TreeCRF BP, complete binary tree, 11 levels, C=2, B=2048.
// Round 6: each wave = 2 batch elements x half-tree. Transitions (batch-
// invariant) are loaded ONCE per wave and reused for both batch elements,
// halving the transition-load + addressing instruction stream per batch.
//  - block = 256 thr = 4 waves; wave w: role r=w>>1 (tree half), pair p=w&1;
//    batches blk*4 + p*2 + {0,1}. 512 blocks -> 2048 waves, 2/SIMD.
//  - lane l owns 15-node subtree under level-7 node 127+64r+l; levels 6..1
//    via __shfl_xor butterfly; root combine via 16-float LDS + 1 barrier.
//  - transitions pre-packed lane-major into d_ws (100 KB, L2-resident).

#define L 2047
#define NSLOT 49
#define PK_ELEMS (2 * NSLOT * 64)

typedef float __attribute__((ext_vector_type(4), aligned(4))) uf4;  // 4B-align ok
typedef float __attribute__((ext_vector_type(2), aligned(4))) uf2;

__device__ __forceinline__ float lse2(float x, float y) {
    float m = fmaxf(x, y);
    return m + __logf(1.0f + __expf(fminf(x, y) - m));
}

__device__ __forceinline__ void up_pair(float c00, float c01, float c10, float c11,
                                        float4 tA, float4 tB, float em0, float em1,
                                        float& o0, float& o1) {
    o0 = em0 + lse2(c00 + tA.x, c01 + tA.y) + lse2(c10 + tB.x, c11 + tB.y);
    o1 = em1 + lse2(c00 + tA.z, c01 + tA.w) + lse2(c10 + tB.z, c11 + tB.w);
}

// (role, slot, lane) -> (dst node, src node): transition float4 tr4[dst*L+src]
__device__ __forceinline__ void slot_decode(int r, int s, int l, int& dst, int& src) {
    const int n7 = 127 + 64 * r + l;
    if (s < 8)       { int k = s >> 1;      dst = 4*n7 + 3 + k;         src = 2*dst + 1 + (s & 1); }
    else if (s < 12) { int j = (s - 8) >> 1;dst = 2*n7 + 1 + j;         src = 2*dst + 1 + (s & 1); }
    else if (s < 14) {                      dst = n7;                   src = 2*n7 + 1 + (s - 12); }
    else if (s < 26) { int d = (s - 14) >> 1; dst = ((n7+1) >> (d+1)) - 1; src = 2*dst + 1 + (s & 1); }
    else if (s < 28) {                      dst = 0;                    src = 1 + (s - 26); }
    else if (s < 34) { int t = s - 27;      dst = ((n7+1) >> (7-t)) - 1; src = (dst - 1) >> 1; }
    else if (s < 35) {                      dst = n7;                   src = (n7 - 1) >> 1; }
    else if (s < 37) {                      dst = 2*n7 + 1 + (s - 35);  src = n7; }
    else if (s < 41) {                      dst = 4*n7 + 3 + (s - 37);  src = (dst - 1) >> 1; }
    else             {                      dst = 8*n7 + 7 + (s - 41);  src = (dst - 1) >> 1; }
}

__global__ void pack_kernel(const float4* __restrict__ tr4, float4* __restrict__ pk) {
    int idx = blockIdx.x * 256 + threadIdx.x;
    if (idx >= PK_ELEMS) return;
    int r = idx / (NSLOT * 64);
    int rem = idx - r * (NSLOT * 64);
    int s = rem >> 6, l = rem & 63;
    int d_, c_; slot_decode(r, s, l, d_, c_);
    pk[idx] = tr4[d_ * L + c_];
}

template <bool UPK>
__global__ __launch_bounds__(256, 2) void treecrf_main(
    const float* __restrict__ emissions,
    const float4* __restrict__ pk,
    const float4* __restrict__ tr4,
    float* __restrict__ out)
{
    __shared__ float sh[16];                 // [p][q][r][c]
    const int tid = threadIdx.x;
    const int l = tid & 63;
    const int w = tid >> 6;
    const int r = w >> 1;                    // tree-half role
    const int p = w & 1;                     // batch-pair index in block
    const int bb = blockIdx.x * 4 + p * 2;   // first batch of this wave

    const float* e0[2]; const float* e1[2]; float* o0[2]; float* o1[2];
    #pragma unroll
    for (int q = 0; q < 2; ++q) {
        e0[q] = emissions + (size_t)(bb + q) * (2 * L);
        e1[q] = e0[q] + L;
        o0[q] = out + (size_t)(bb + q) * (2 * L);
        o1[q] = o0[q] + L;
    }

    auto FL = [&](int s) -> float4 {
        if (UPK) return pk[((r * NSLOT + s) << 6) + l];
        int d_, c_; slot_decode(r, s, l, d_, c_);
        return tr4[d_ * L + c_];
    };

    // ---- emissions (per batch q) ----
    float el0[2][8], el1[2][8];
    float em9_0[2][4], em9_1[2][4], em8_0[2][2], em8_1[2][2], em7_0[2], em7_1[2];
    float Ea0[2][7], Ea1[2][7];
    #pragma unroll
    for (int q = 0; q < 2; ++q) {
        const uf4* pA = (const uf4*)(e0[q] + 1023 + 512*r + 8*l);
        const uf4* pB = (const uf4*)(e1[q] + 1023 + 512*r + 8*l);
        uf4 a = pA[0], b2 = pA[1], c = pB[0], d = pB[1];
        el0[q][0]=a.x;  el0[q][1]=a.y;  el0[q][2]=a.z;  el0[q][3]=a.w;
        el0[q][4]=b2.x; el0[q][5]=b2.y; el0[q][6]=b2.z; el0[q][7]=b2.w;
        el1[q][0]=c.x;  el1[q][1]=c.y;  el1[q][2]=c.z;  el1[q][3]=c.w;
        el1[q][4]=d.x;  el1[q][5]=d.y;  el1[q][6]=d.z;  el1[q][7]=d.w;
        uf4 a9 = *(const uf4*)(e0[q] + 511 + 256*r + 4*l);
        uf4 c9 = *(const uf4*)(e1[q] + 511 + 256*r + 4*l);
        em9_0[q][0]=a9.x; em9_0[q][1]=a9.y; em9_0[q][2]=a9.z; em9_0[q][3]=a9.w;
        em9_1[q][0]=c9.x; em9_1[q][1]=c9.y; em9_1[q][2]=c9.z; em9_1[q][3]=c9.w;
        uf2 g = *(const uf2*)(e0[q] + 255 + 128*r + 2*l);
        uf2 h = *(const uf2*)(e1[q] + 255 + 128*r + 2*l);
        em8_0[q][0]=g.x; em8_0[q][1]=g.y; em8_1[q][0]=h.x; em8_1[q][1]=h.y;
        em7_0[q] = e0[q][127 + 64*r + l]; em7_1[q] = e1[q][127 + 64*r + l];
        Ea0[q][0] = e0[q][0]; Ea1[q][0] = e1[q][0];
        #pragma unroll
        for (int t = 1; t <= 6; ++t) {
            const int n = ((128 + 64*r + l) >> (7 - t)) - 1;
            Ea0[q][t] = e0[q][n]; Ea1[q][t] = e1[q][n];
        }
    }

    // ---- up: local subtree (levels 10->7); transitions shared across q ----
    float A9_0[2][4], A9_1[2][4];
    #pragma unroll
    for (int k = 0; k < 4; ++k) {
        float4 tA = FL(2*k), tB = FL(2*k + 1);
        #pragma unroll
        for (int q = 0; q < 2; ++q)
            up_pair(el0[q][2*k], el1[q][2*k], el0[q][2*k+1], el1[q][2*k+1], tA, tB,
                    em9_0[q][k], em9_1[q][k], A9_0[q][k], A9_1[q][k]);
    }
    float A8_0[2][2], A8_1[2][2];
    #pragma unroll
    for (int j = 0; j < 2; ++j) {
        float4 tA = FL(8 + 2*j), tB = FL(9 + 2*j);
        #pragma unroll
        for (int q = 0; q < 2; ++q)
            up_pair(A9_0[q][2*j], A9_1[q][2*j], A9_0[q][2*j+1], A9_1[q][2*j+1], tA, tB,
                    em8_0[q][j], em8_1[q][j], A8_0[q][j], A8_1[q][j]);
    }
    float A7_0[2], A7_1[2];
    {
        float4 tA = FL(12), tB = FL(13);
        #pragma unroll
        for (int q = 0; q < 2; ++q)
            up_pair(A8_0[q][0], A8_1[q][0], A8_0[q][1], A8_1[q][1], tA, tB,
                    em7_0[q], em7_1[q], A7_0[q], A7_1[q]);
    }

    // ---- up butterfly: levels 6..1 ----
    float cur0[2] = {A7_0[0], A7_0[1]}, cur1[2] = {A7_1[0], A7_1[1]};
    float Aa0[2][7], Aa1[2][7];
    #pragma unroll
    for (int d = 0; d < 6; ++d) {
        const int t = 6 - d;
        float4 tL = FL(14 + 2*d), tR = FL(15 + 2*d);
        bool isL = ((l >> d) & 1) == 0;
        #pragma unroll
        for (int q = 0; q < 2; ++q) {
            float p0v = __shfl_xor(cur0[q], 1 << d);
            float p1v = __shfl_xor(cur1[q], 1 << d);
            float Lc0 = isL ? cur0[q] : p0v, Lc1 = isL ? cur1[q] : p1v;
            float Rc0 = isL ? p0v : cur0[q], Rc1 = isL ? p1v : cur1[q];
            up_pair(Lc0, Lc1, Rc0, Rc1, tL, tR, Ea0[q][t], Ea1[q][t],
                    cur0[q], cur1[q]);
            Aa0[q][t] = cur0[q]; Aa1[q][t] = cur1[q];
        }
    }

    // ---- root combine across the two role-waves of this pair ----
    if (l == 0) {
        #pragma unroll
        for (int q = 0; q < 2; ++q) {
            sh[p*8 + q*4 + r*2 + 0] = cur0[q];
            sh[p*8 + q*4 + r*2 + 1] = cur1[q];
        }
    }
    __syncthreads();
    {
        float4 t1 = FL(26), t2 = FL(27);
        if (r == 0 && l == 0) {
            #pragma unroll
            for (int q = 0; q < 2; ++q) {
                float a1_0 = sh[p*8 + q*4 + 0], a1_1 = sh[p*8 + q*4 + 1];
                float a2_0 = sh[p*8 + q*4 + 2], a2_1 = sh[p*8 + q*4 + 3];
                float AR0 = Ea0[q][0] + lse2(a1_0 + t1.x, a1_1 + t1.y)
                                      + lse2(a2_0 + t2.x, a2_1 + t2.y);
                float AR1 = Ea1[q][0] + lse2(a1_0 + t1.z, a1_1 + t1.w)
                                      + lse2(a2_0 + t2.z, a2_1 + t2.w);
                float m = lse2(AR0, AR1);
                o0[q][0] = AR0 - m; o1[q][0] = AR1 - m;
            }
        }
    }

    // ---- down: ancestor chain levels 1..6 ----
    float D0[2], D1[2];
    #pragma unroll
    for (int q = 0; q < 2; ++q) { D0[q] = Ea0[q][0]; D1[q] = Ea1[q][0]; }
    #pragma unroll
    for (int t = 1; t <= 6; ++t) {
        float4 td = FL(27 + t);
        const bool emit = (l & ((1 << (7 - t)) - 1)) == 0;
        const int n = ((128 + 64*r + l) >> (7 - t)) - 1;
        #pragma unroll
        for (int q = 0; q < 2; ++q) {
            float b0v = lse2(D0[q] + td.x, D1[q] + td.y);
            float b1v = lse2(D0[q] + td.z, D1[q] + td.w);
            float s0 = Aa0[q][t] + b0v, s1 = Aa1[q][t] + b1v, m = lse2(s0, s1);
            if (emit) { o0[q][n] = s0 - m; o1[q][n] = s1 - m; }
            D0[q] = Ea0[q][t] + b0v; D1[q] = Ea1[q][t] + b1v;
        }
    }

    // ---- level 7 (own node) ----
    {
        float4 td = FL(34);
        #pragma unroll
        for (int q = 0; q < 2; ++q) {
            float b0v = lse2(D0[q] + td.x, D1[q] + td.y);
            float b1v = lse2(D0[q] + td.z, D1[q] + td.w);
            float s0 = A7_0[q] + b0v, s1 = A7_1[q] + b1v, m = lse2(s0, s1);
            o0[q][127 + 64*r + l] = s0 - m; o1[q][127 + 64*r + l] = s1 - m;
            D0[q] = em7_0[q] + b0v; D1[q] = em7_1[q] + b1v;
        }
    }

    // ---- level 8 ----
    float D8_0[2][2], D8_1[2][2];
    {
        float w0[2][2], w1[2][2];
        #pragma unroll
        for (int j = 0; j < 2; ++j) {
            float4 td = FL(35 + j);
            #pragma unroll
            for (int q = 0; q < 2; ++q) {
                float b0v = lse2(D0[q] + td.x, D1[q] + td.y);
                float b1v = lse2(D0[q] + td.z, D1[q] + td.w);
                float s0 = A8_0[q][j] + b0v, s1 = A8_1[q][j] + b1v, m = lse2(s0, s1);
                w0[q][j] = s0 - m; w1[q][j] = s1 - m;
                D8_0[q][j] = em8_0[q][j] + b0v; D8_1[q][j] = em8_1[q][j] + b1v;
            }
        }
        #pragma unroll
        for (int q = 0; q < 2; ++q) {
            *(uf2*)(o0[q] + 255 + 128*r + 2*l) = uf2{w0[q][0], w0[q][1]};
            *(uf2*)(o1[q] + 255 + 128*r + 2*l) = uf2{w1[q][0], w1[q][1]};
        }
    }

    // ---- level 9 ----
    float D9_0[2][4], D9_1[2][4];
    {
        float w0[2][4], w1[2][4];
        #pragma unroll
        for (int k = 0; k < 4; ++k) {
            float4 td = FL(37 + k);
            #pragma unroll
            for (int q = 0; q < 2; ++q) {
                float b0v = lse2(D8_0[q][k>>1] + td.x, D8_1[q][k>>1] + td.y);
                float b1v = lse2(D8_0[q][k>>1] + td.z, D8_1[q][k>>1] + td.w);
                float s0 = A9_0[q][k] + b0v, s1 = A9_1[q][k] + b1v, m = lse2(s0, s1);
                w0[q][k] = s0 - m; w1[q][k] = s1 - m;
                D9_0[q][k] = em9_0[q][k] + b0v; D9_1[q][k] = em9_1[q][k] + b1v;
            }
        }
        #pragma unroll
        for (int q = 0; q < 2; ++q) {
            *(uf4*)(o0[q] + 511 + 256*r + 4*l) = uf4{w0[q][0], w0[q][1], w0[q][2], w0[q][3]};
            *(uf4*)(o1[q] + 511 + 256*r + 4*l) = uf4{w1[q][0], w1[q][1], w1[q][2], w1[q][3]};
        }
    }

    // ---- level 10 (leaves; A_leaf = emission) ----
    {
        float w0[2][8], w1[2][8];
        #pragma unroll
        for (int m2 = 0; m2 < 8; ++m2) {
            float4 td = FL(41 + m2);
            #pragma unroll
            for (int q = 0; q < 2; ++q) {
                float b0v = lse2(D9_0[q][m2>>1] + td.x, D9_1[q][m2>>1] + td.y);
                float b1v = lse2(D9_0[q][m2>>1] + td.z, D9_1[q][m2>>1] + td.w);
                float s0 = el0[q][m2] + b0v, s1 = el1[q][m2] + b1v, m = lse2(s0, s1);
                w0[q][m2] = s0 - m; w1[q][m2] = s1 - m;
            }
        }
        #pragma unroll
        for (int q = 0; q < 2; ++q) {
            uf4* q0 = (uf4*)(o0[q] + 1023 + 512*r + 8*l);
            uf4* q1 = (uf4*)(o1[q] + 1023 + 512*r + 8*l);
            q0[0] = uf4{w0[q][0], w0[q][1], w0[q][2], w0[q][3]};
            q0[1] = uf4{w0[q][4], w0[q][5], w0[q][6], w0[q][7]};
            q1[0] = uf4{w1[q][0], w1[q][1], w1[q][2], w1[q][3]};
            q1[1] = uf4{w1[q][4], w1[q][5], w1[q][6], w1[q][7]};
        }
    }
}

extern "C" void kernel_launch(void* const* d_in, const int* in_sizes, int n_in,
                              void* d_out, int out_size, void* d_ws, size_t ws_size,
                              hipStream_t stream) {
    const float* emissions = (const float*)d_in[0];
    const float4* tr4 = (const float4*)d_in[1];
    float* out = (float*)d_out;

    const size_t packed_bytes = (size_t)PK_ELEMS * sizeof(float4);   // ~100 KB
    const bool use_ws = (ws_size >= packed_bytes) && (d_ws != nullptr);
    if (use_ws) {
        float4* pk = (float4*)d_ws;
        pack_kernel<<<(PK_ELEMS + 255) / 256, 256, 0, stream>>>(tr4, pk);
        treecrf_main<true><<<512, 256, 0, stream>>>(emissions, pk, tr4, out);
    } else {
        treecrf_main<false><<<512, 256, 0, stream>>>(emissions, nullptr, tr4, out);
    }
}

// Round 7
// 131.223 us; speedup vs baseline: 1.0412x; 1.0412x over previous
//
#include <hip/hip_runtime.h>

// TreeCRF BP, complete binary tree, 11 levels, C=2, B=2048.
// Round 7: R5 skeleton (2 waves per batch element, half-tree each) +
// E-FORM MATH: transitions are stored as E = exp(T) (precomputed in the
// batch-invariant pack kernel), so each edge message becomes
//   contrib[cd] = m + log(p0*E[cd][0] + p1*E[cd][1]),
// with m/p0/p1 computed once per SOURCE node and shared across both
// destination classes, and the two child-logs of an up-node fused into one
// (log(SL*SR)). Cuts transcendental count ~30% and ALU ~25% vs lse2-form.

#define L 2047
#define NSLOT 49
#define PK_ELEMS (2 * NSLOT * 64)

typedef float __attribute__((ext_vector_type(4), aligned(4))) uf4;  // 4B-align ok
typedef float __attribute__((ext_vector_type(2), aligned(4))) uf2;

__device__ __forceinline__ float lse2(float x, float y) {
    float m = fmaxf(x, y);
    return m + __logf(1.0f + __expf(fminf(x, y) - m));
}

// up-node: children (c00,c01) / (c10,c11), EDGE-EXP tables EA/EB, emission.
__device__ __forceinline__ void up_pair_e(float c00, float c01, float c10, float c11,
                                          float4 EA, float4 EB, float em0, float em1,
                                          float& o0, float& o1) {
    float mA = fmaxf(c00, c01), mB = fmaxf(c10, c11);
    float pA0 = __expf(c00 - mA), pA1 = __expf(c01 - mA);
    float pB0 = __expf(c10 - mB), pB1 = __expf(c11 - mB);
    float SA0 = pA0 * EA.x + pA1 * EA.y, SA1 = pA0 * EA.z + pA1 * EA.w;
    float SB0 = pB0 * EB.x + pB1 * EB.y, SB1 = pB0 * EB.z + pB1 * EB.w;
    float base = mA + mB;
    o0 = em0 + base + __logf(SA0 * SB0);
    o1 = em1 + base + __logf(SA1 * SB1);
}

// down message: parent D=(D0,D1)=em+beta, edge-exp E -> child betas (b0,b1)
__device__ __forceinline__ void dn_msg(float D0, float D1, float4 E,
                                       float& b0, float& b1) {
    float m = fmaxf(D0, D1);
    float p0 = __expf(D0 - m), p1 = __expf(D1 - m);
    b0 = m + __logf(p0 * E.x + p1 * E.y);
    b1 = m + __logf(p0 * E.z + p1 * E.w);
}

// (role, slot, lane) -> (dst node, src node): transition float4 tr4[dst*L+src]
__device__ __forceinline__ void slot_decode(int r, int s, int l, int& dst, int& src) {
    const int n7 = 127 + 64 * r + l;
    if (s < 8)       { int k = s >> 1;      dst = 4*n7 + 3 + k;         src = 2*dst + 1 + (s & 1); }
    else if (s < 12) { int j = (s - 8) >> 1;dst = 2*n7 + 1 + j;         src = 2*dst + 1 + (s & 1); }
    else if (s < 14) {                      dst = n7;                   src = 2*n7 + 1 + (s - 12); }
    else if (s < 26) { int d = (s - 14) >> 1; dst = ((n7+1) >> (d+1)) - 1; src = 2*dst + 1 + (s & 1); }
    else if (s < 28) {                      dst = 0;                    src = 1 + (s - 26); }
    else if (s < 34) { int t = s - 27;      dst = ((n7+1) >> (7-t)) - 1; src = (dst - 1) >> 1; }
    else if (s < 35) {                      dst = n7;                   src = (n7 - 1) >> 1; }
    else if (s < 37) {                      dst = 2*n7 + 1 + (s - 35);  src = n7; }
    else if (s < 41) {                      dst = 4*n7 + 3 + (s - 37);  src = (dst - 1) >> 1; }
    else             {                      dst = 8*n7 + 7 + (s - 41);  src = (dst - 1) >> 1; }
}

__global__ void pack_kernel(const float4* __restrict__ tr4, float4* __restrict__ pk) {
    int idx = blockIdx.x * 256 + threadIdx.x;
    if (idx >= PK_ELEMS) return;
    int r = idx / (NSLOT * 64);
    int rem = idx - r * (NSLOT * 64);
    int s = rem >> 6, l = rem & 63;
    int d_, c_; slot_decode(r, s, l, d_, c_);
    float4 t = tr4[d_ * L + c_];
    pk[idx] = float4{__expf(t.x), __expf(t.y), __expf(t.z), __expf(t.w)};
}

template <bool UPK>
__global__ __launch_bounds__(128, 4) void treecrf_main(
    const float* __restrict__ emissions,
    const float4* __restrict__ pk,
    const float4* __restrict__ tr4,
    float* __restrict__ out)
{
    __shared__ float sh[4];
    const int tid = threadIdx.x;
    const int l = tid & 63;
    const int r = tid >> 6;                // wave role: half-tree under node 1+r
    const int b = blockIdx.x;
    const float* __restrict__ e0 = emissions + (size_t)b * (2 * L);
    const float* __restrict__ e1 = e0 + L;
    float* __restrict__ o0 = out + (size_t)b * (2 * L);
    float* __restrict__ o1 = o0 + L;

    auto FL = [&](int s) -> float4 {
        if (UPK) return pk[((r * NSLOT + s) << 6) + l];
        int d_, c_; slot_decode(r, s, l, d_, c_);
        float4 t = tr4[d_ * L + c_];
        return float4{__expf(t.x), __expf(t.y), __expf(t.z), __expf(t.w)};
    };

    // ---- emissions ----
    float el0[8], el1[8];                                  // leaves 8n7+7+m
    {
        const uf4* p0 = (const uf4*)(e0 + 1023 + 512*r + 8*l);
        const uf4* p1 = (const uf4*)(e1 + 1023 + 512*r + 8*l);
        uf4 a = p0[0], c = p0[1], d = p1[0], e = p1[1];
        el0[0]=a.x; el0[1]=a.y; el0[2]=a.z; el0[3]=a.w;
        el0[4]=c.x; el0[5]=c.y; el0[6]=c.z; el0[7]=c.w;
        el1[0]=d.x; el1[1]=d.y; el1[2]=d.z; el1[3]=d.w;
        el1[4]=e.x; el1[5]=e.y; el1[6]=e.z; el1[7]=e.w;
    }
    float em9_0[4], em9_1[4], em8_0[2], em8_1[2], em7_0, em7_1;
    {
        uf4 a = *(const uf4*)(e0 + 511 + 256*r + 4*l);
        uf4 c = *(const uf4*)(e1 + 511 + 256*r + 4*l);
        em9_0[0]=a.x; em9_0[1]=a.y; em9_0[2]=a.z; em9_0[3]=a.w;
        em9_1[0]=c.x; em9_1[1]=c.y; em9_1[2]=c.z; em9_1[3]=c.w;
        uf2 g = *(const uf2*)(e0 + 255 + 128*r + 2*l);
        uf2 h = *(const uf2*)(e1 + 255 + 128*r + 2*l);
        em8_0[0]=g.x; em8_0[1]=g.y; em8_1[0]=h.x; em8_1[1]=h.y;
        em7_0 = e0[127 + 64*r + l]; em7_1 = e1[127 + 64*r + l];
    }
    float Ea0[7], Ea1[7];                                  // [0]=root, [t]=ancestor lvl t
    Ea0[0] = e0[0]; Ea1[0] = e1[0];
    #pragma unroll
    for (int t = 1; t <= 6; ++t) {
        const int n = ((128 + 64*r + l) >> (7 - t)) - 1;
        Ea0[t] = e0[n]; Ea1[t] = e1[n];
    }

    // ---- up: local subtree (levels 10->7) ----
    float A9_0[4], A9_1[4];
    #pragma unroll
    for (int k = 0; k < 4; ++k)
        up_pair_e(el0[2*k], el1[2*k], el0[2*k+1], el1[2*k+1], FL(2*k), FL(2*k+1),
                  em9_0[k], em9_1[k], A9_0[k], A9_1[k]);
    float A8_0[2], A8_1[2];
    #pragma unroll
    for (int j = 0; j < 2; ++j)
        up_pair_e(A9_0[2*j], A9_1[2*j], A9_0[2*j+1], A9_1[2*j+1], FL(8+2*j), FL(9+2*j),
                  em8_0[j], em8_1[j], A8_0[j], A8_1[j]);
    float A7_0, A7_1;
    up_pair_e(A8_0[0], A8_1[0], A8_0[1], A8_1[1], FL(12), FL(13), em7_0, em7_1, A7_0, A7_1);

    // ---- up butterfly: levels 6..1 within the wave ----
    float cur0 = A7_0, cur1 = A7_1;
    float Aa0[7], Aa1[7];                                  // [t]=A at ancestor lvl t
    #pragma unroll
    for (int d = 0; d < 6; ++d) {
        const int t = 6 - d;
        float p0v = __shfl_xor(cur0, 1 << d);
        float p1v = __shfl_xor(cur1, 1 << d);
        bool isL = ((l >> d) & 1) == 0;
        float Lc0 = isL ? cur0 : p0v, Lc1 = isL ? cur1 : p1v;
        float Rc0 = isL ? p0v : cur0, Rc1 = isL ? p1v : cur1;
        up_pair_e(Lc0, Lc1, Rc0, Rc1, FL(14 + 2*d), FL(15 + 2*d),
                  Ea0[t], Ea1[t], cur0, cur1);
        Aa0[t] = cur0; Aa1[t] = cur1;
    }

    // ---- root combine across waves (16 B LDS handoff) ----
    if (l == 0) { sh[2*r] = cur0; sh[2*r + 1] = cur1; }
    __syncthreads();
    if (r == 0 && l == 0) {
        float AR0, AR1;
        up_pair_e(sh[0], sh[1], sh[2], sh[3], FL(26), FL(27),
                  Ea0[0], Ea1[0], AR0, AR1);
        float m = lse2(AR0, AR1);
        o0[0] = AR0 - m; o1[0] = AR1 - m;
    }

    // ---- down: ancestor chain levels 1..6 ----
    float D0 = Ea0[0], D1 = Ea1[0];                        // root em + beta(=0)
    #pragma unroll
    for (int t = 1; t <= 6; ++t) {
        float b0, b1;
        dn_msg(D0, D1, FL(27 + t), b0, b1);
        float s0 = Aa0[t] + b0, s1 = Aa1[t] + b1, m = lse2(s0, s1);
        if ((l & ((1 << (7 - t)) - 1)) == 0) {
            const int n = ((128 + 64*r + l) >> (7 - t)) - 1;
            o0[n] = s0 - m; o1[n] = s1 - m;
        }
        D0 = Ea0[t] + b0; D1 = Ea1[t] + b1;
    }

    // ---- level 7 (own node) ----
    {
        float b0, b1;
        dn_msg(D0, D1, FL(34), b0, b1);
        float s0 = A7_0 + b0, s1 = A7_1 + b1, m = lse2(s0, s1);
        o0[127 + 64*r + l] = s0 - m; o1[127 + 64*r + l] = s1 - m;
        D0 = em7_0 + b0; D1 = em7_1 + b1;
    }

    // ---- level 8 ----
    float D8_0[2], D8_1[2];
    {
        float w0[2], w1[2];
        #pragma unroll
        for (int j = 0; j < 2; ++j) {
            float b0, b1;
            dn_msg(D0, D1, FL(35 + j), b0, b1);
            float s0 = A8_0[j] + b0, s1 = A8_1[j] + b1, m = lse2(s0, s1);
            w0[j] = s0 - m; w1[j] = s1 - m;
            D8_0[j] = em8_0[j] + b0; D8_1[j] = em8_1[j] + b1;
        }
        *(uf2*)(o0 + 255 + 128*r + 2*l) = uf2{w0[0], w0[1]};
        *(uf2*)(o1 + 255 + 128*r + 2*l) = uf2{w1[0], w1[1]};
    }

    // ---- level 9 ----
    float D9_0[4], D9_1[4];
    {
        float w0[4], w1[4];
        #pragma unroll
        for (int k = 0; k < 4; ++k) {
            float b0, b1;
            dn_msg(D8_0[k>>1], D8_1[k>>1], FL(37 + k), b0, b1);
            float s0 = A9_0[k] + b0, s1 = A9_1[k] + b1, m = lse2(s0, s1);
            w0[k] = s0 - m; w1[k] = s1 - m;
            D9_0[k] = em9_0[k] + b0; D9_1[k] = em9_1[k] + b1;
        }
        *(uf4*)(o0 + 511 + 256*r + 4*l) = uf4{w0[0], w0[1], w0[2], w0[3]};
        *(uf4*)(o1 + 511 + 256*r + 4*l) = uf4{w1[0], w1[1], w1[2], w1[3]};
    }

    // ---- level 10 (leaves; A_leaf = emission) ----
    {
        float w0[8], w1[8];
        #pragma unroll
        for (int m2 = 0; m2 < 8; ++m2) {
            float b0, b1;
            dn_msg(D9_0[m2>>1], D9_1[m2>>1], FL(41 + m2), b0, b1);
            float s0 = el0[m2] + b0, s1 = el1[m2] + b1, m = lse2(s0, s1);
            w0[m2] = s0 - m; w1[m2] = s1 - m;
        }
        uf4* q0 = (uf4*)(o0 + 1023 + 512*r + 8*l);
        uf4* q1 = (uf4*)(o1 + 1023 + 512*r + 8*l);
        q0[0] = uf4{w0[0], w0[1], w0[2], w0[3]}; q0[1] = uf4{w0[4], w0[5], w0[6], w0[7]};
        q1[0] = uf4{w1[0], w1[1], w1[2], w1[3]}; q1[1] = uf4{w1[4], w1[5], w1[6], w1[7]};
    }
}

extern "C" void kernel_launch(void* const* d_in, const int* in_sizes, int n_in,
                              void* d_out, int out_size, void* d_ws, size_t ws_size,
                              hipStream_t stream) {
    const float* emissions = (const float*)d_in[0];
    const float4* tr4 = (const float4*)d_in[1];
    float* out = (float*)d_out;

    const size_t packed_bytes = (size_t)PK_ELEMS * sizeof(float4);   // ~100 KB
    const bool use_ws = (ws_size >= packed_bytes) && (d_ws != nullptr);
    if (use_ws) {
        float4* pk = (float4*)d_ws;
        pack_kernel<<<(PK_ELEMS + 255) / 256, 256, 0, stream>>>(tr4, pk);
        treecrf_main<true><<<2048, 128, 0, stream>>>(emissions, pk, tr4, out);
    } else {
        treecrf_main<false><<<2048, 128, 0, stream>>>(emissions, nullptr, tr4, out);
    }
}